// Round 15
// baseline (532.382 us; speedup 1.0000x reference)
//
#include <hip/hip_runtime.h>
#include <hip/hip_bf16.h>
#include <math.h>

// Round 15: M=4 rows/wave, f16 dot2 front, fused QKV, natural regalloc (no hint).
// Rationale: r10/r13/r14 all pin ~515us across issue counts -> latency-bound; M=4 gives
// each weight load 4 independent consumer chains and halves per-row weight loads.
//  pack_weights: W1,W2 -> bf16 MFMA B-frag tables (proven)
//  pack16:       front weights -> f16 chunk-of-4 tables + f32 fused QKV bias
//  ace_front4:   branches + fused-QKV + attn + Wo + LN, f32 accum / f16 data -> xg bf16
//  ace_mlp:      proven MFMA MLP
// B=131072, E=64, H=4, D=16, S=5. Out: (B,160) fp32.

#define NROWS 131072
#define M 4
#define WAVES 4
#define BROWS 128

typedef __attribute__((ext_vector_type(8))) short short8;
typedef __attribute__((ext_vector_type(4))) float f32x4;
typedef __attribute__((ext_vector_type(4))) _Float16 half4;

__device__ __forceinline__ short f2bs(float f) {
  __hip_bfloat16 h = __float2bfloat16(f);
  return *reinterpret_cast<short*>(&h);
}

__device__ __forceinline__ float dot4(half4 a, half4 b, float c) {
#if __has_builtin(__builtin_amdgcn_fdot2)
  c = __builtin_amdgcn_fdot2(__builtin_shufflevector(a, a, 0, 1),
                             __builtin_shufflevector(b, b, 0, 1), c, false);
  c = __builtin_amdgcn_fdot2(__builtin_shufflevector(a, a, 2, 3),
                             __builtin_shufflevector(b, b, 2, 3), c, false);
#else
  c += (float)a.x * (float)b.x; c += (float)a.y * (float)b.y;
  c += (float)a.z * (float)b.z; c += (float)a.w * (float)b.w;
#endif
  return c;
}

#define MFMA __builtin_amdgcn_mfma_f32_16x16x32_bf16
#define GLOAD_LDS16(g, l) __builtin_amdgcn_global_load_lds( \
    (const __attribute__((address_space(1))) void*)(g),     \
    (__attribute__((address_space(3))) void*)(l), 16, 0, 0)

// f16 table layout (element offsets):
//  WPT 0..3776, WUT ..14016, WFT ..44736 (fused Wu.Wqkv, [s][3][JCNT][64][4]), WOT ..48832
#define OFF_WUT16  3776
#define OFF_WFT16  14016
#define OFF_WOT16  44736
#define WT16_N     48832
// f32 BQF[5][3][64] follows (element count 960)
#define PACK_N     (WT16_N + 960)

// ---------------- pack 1: W1,W2 -> bf16 fragment-ordered (proven) ----------------
__global__ void pack_weights(const float* __restrict__ W1, const float* __restrict__ W2,
                             short* __restrict__ ws) {
  int idx = blockIdx.x * blockDim.x + threadIdx.x;
  if (idx < 81920) {
    int i = idx & 7, lane = (idx >> 3) & 63;
    int t = idx >> 9;                 // ntg*10 + kk
    int kk = t % 10, ntg = t / 10;
    int n = ntg * 16 + (lane & 15);
    int k = kk * 32 + (lane >> 4) * 8 + i;
    ws[idx] = f2bs(W1[k * 256 + n]);
  } else if (idx < 81920 + 40960) {
    int j = idx - 81920;
    int i = j & 7, lane = (j >> 3) & 63;
    int t = j >> 9;                   // ntg*8 + kk
    int kk = t & 7, ntg = t >> 3;
    int n = ntg * 16 + (lane & 15);
    int k = kk * 32 + (lane >> 4) * 8 + i;
    ws[81920 + j] = f2bs(W2[k * 160 + n]);
  }
}

// ---------------- pack 16: f16 front tables + f32 fused QKV bias ----------------
__global__ void pack16(
    const float* __restrict__ Wv_p, const float* __restrict__ Wa_p,
    const float* __restrict__ Wp_p, const float* __restrict__ Ws_p,
    const float* __restrict__ Wt_p,
    const float* __restrict__ Wv_u, const float* __restrict__ Wa_u,
    const float* __restrict__ Wp_u, const float* __restrict__ Ws_u,
    const float* __restrict__ Wt_u,
    const float* __restrict__ bv_u, const float* __restrict__ ba_u,
    const float* __restrict__ bp_u, const float* __restrict__ bs_u,
    const float* __restrict__ bt_u,
    const float* __restrict__ Wq, const float* __restrict__ Wk,
    const float* __restrict__ Wvv,
    const float* __restrict__ bq, const float* __restrict__ bk,
    const float* __restrict__ bvv,
    const float* __restrict__ Wo,
    _Float16* __restrict__ wt, float* __restrict__ bqf)
{
  int idx = blockIdx.x * blockDim.x + threadIdx.x;
  if (idx >= PACK_N) return;
  const float* WP[5] = {Wv_p, Wa_p, Wp_p, Ws_p, Wt_p};
  const float* WU[5] = {Wv_u, Wa_u, Wp_u, Ws_u, Wt_u};
  const float* BU[5] = {bv_u, ba_u, bp_u, bs_u, bt_u};
  const float* WT3[3] = {Wq, Wk, Wvv};
  const float* BT3[3] = {bq, bk, bvv};
  const int INs[5]  = {14, 17, 51, 7, 10};
  const int HIDs[5] = {32, 64, 32, 16, 16};
  const int ICNT[5] = {4, 5, 13, 2, 3};
  const int JCNT[5] = {8, 16, 8, 4, 4};

  if (idx < OFF_WUT16) {
    int r = idx, s = 0;
    while (r >= ICNT[s] * HIDs[s] * 4) { r -= ICNT[s] * HIDs[s] * 4; ++s; }
    int ic = r / (HIDs[s] * 4);
    int j  = (r / 4) % HIDs[s];
    int c  = r & 3;
    int i  = ic * 4 + c;
    wt[idx] = (_Float16)((i < INs[s]) ? WP[s][i * HIDs[s] + j] : 0.f);
  } else if (idx < OFF_WFT16) {
    int r = idx - OFF_WUT16, s = 0;
    while (r >= JCNT[s] * 256) { r -= JCNT[s] * 256; ++s; }
    int jc = r / 256;
    int e  = (r / 4) & 63;
    int c  = r & 3;
    wt[idx] = (_Float16)(WU[s][(jc * 4 + c) * 64 + e]);
  } else if (idx < OFF_WOT16) {
    int r = idx - OFF_WFT16, s = 0;
    while (r >= 3 * JCNT[s] * 256) { r -= 3 * JCNT[s] * 256; ++s; }
    int t  = r / (JCNT[s] * 256);
    int r2 = r % (JCNT[s] * 256);
    int jc = r2 / 256;
    int hd = (r2 / 4) & 63;
    int c  = r2 & 3;
    int j  = jc * 4 + c;
    float acc = 0.f;
    for (int e = 0; e < 64; ++e) acc += WU[s][j * 64 + e] * WT3[t][e * 64 + hd];
    wt[idx] = (_Float16)acc;
  } else if (idx < WT16_N) {
    int r = idx - OFF_WOT16;
    int hdc = r >> 8;
    int e   = (r >> 2) & 63;
    int c   = r & 3;
    wt[idx] = (_Float16)(Wo[(hdc * 4 + c) * 64 + e]);
  } else {
    int c = idx - WT16_N;               // [0,960)
    int s = c / 192, rem = c % 192, t = rem >> 6, hd = rem & 63;
    float acc = BT3[t][hd];
    for (int e = 0; e < 64; ++e) acc += BU[s][e] * WT3[t][e * 64 + hd];
    bqf[c] = acc;
  }
}

// ================= kernel A: front, f16 dot2, fused QKV, M=4, natural regalloc =================
__global__ __launch_bounds__(256) void ace_front4(
    const float* __restrict__ visual, const float* __restrict__ audio,
    const float* __restrict__ pose,   const float* __restrict__ spatial,
    const float* __restrict__ timex,
    const float* __restrict__ bv_p, const float* __restrict__ ba_p,
    const float* __restrict__ bp_p, const float* __restrict__ bs_p,
    const float* __restrict__ bt_p,
    const float* __restrict__ bv_u, const float* __restrict__ ba_u,
    const float* __restrict__ bp_u, const float* __restrict__ bs_u,
    const float* __restrict__ bt_u,
    const float* __restrict__ bo,
    const float* __restrict__ gamma, const float* __restrict__ beta,
    const _Float16* __restrict__ WT, const float* __restrict__ BQF,
    char* __restrict__ xg)   // bf16 [NROWS][320], byte (col*2)^((row&7)<<4)
{
  // per-wave f16 LDS (3648 elems = 7296 B):
  //   in @0 [m][112] (448), h @448 [m][160] (640), x @1088 [m][5][64] (1280), o @2368 [m][5][64] (1280)
  __shared__ __align__(16) _Float16 lds[WAVES][3648];
  const int tid  = threadIdx.x;
  const int wave = tid >> 6;
  const int lane = tid & 63;
  _Float16* A  = lds[wave];
  _Float16* Hh = A + 448;
  _Float16* X  = A + 1088;
  _Float16* O  = A + 2368;
  const int rowBase = (blockIdx.x * WAVES + wave) * M;

  const int HIDs[5] = {32, 64, 32, 16, 16};
  const int ICNT[5] = {4, 5, 13, 2, 3};
  const int JCNT[5] = {8, 16, 8, 4, 4};
  const int IOFF[5] = {0, 16, 36, 92, 100};
  const int HOFF[5] = {0, 32, 96, 128, 144};
  const int WPT_OFF[5] = {0, 512, 1792, 3456, 3584};
  const int WUT_OFF[5] = {0, 2048, 6144, 8192, 9216};
  const int WFT_OFF[5] = {0, 6144, 18432, 24576, 27648};
  const float* BP[5] = {bv_p, ba_p, bp_p, bs_p, bt_p};
  const float* BU[5] = {bv_u, ba_u, bp_u, bs_u, bt_u};

  // ---- zero padded input region [0..448), then stage raw inputs as f16 ----
  #pragma unroll
  for (int k2 = 0; k2 < 7; ++k2) A[k2 * 64 + lane] = (_Float16)0.f;
  #pragma unroll
  for (int m = 0; m < M; ++m) {
    const int r = rowBase + m;
    if (lane < 14) A[m * 112 +   0 + lane] = (_Float16)visual [r * 14 + lane];
    if (lane < 17) A[m * 112 +  16 + lane] = (_Float16)audio  [r * 17 + lane];
    if (lane < 51) A[m * 112 +  36 + lane] = (_Float16)pose   [r * 51 + lane];
    if (lane <  7) A[m * 112 +  92 + lane] = (_Float16)spatial[r *  7 + lane];
    if (lane < 10) A[m * 112 + 100 + lane] = (_Float16)timex  [r * 10 + lane];
  }

  // ---- proj (relu) + upsample per modality ----
  #pragma unroll
  for (int s = 0; s < 5; ++s) {
    const int hid = HIDs[s];
    if (lane < hid) {
      const float bp = BP[s][lane];
      float a[M];
      #pragma unroll
      for (int m = 0; m < M; ++m) a[m] = bp;
      const _Float16* wp = WT + WPT_OFF[s];
      #pragma unroll
      for (int ic = 0; ic < ICNT[s]; ++ic) {
        half4 w = *(const half4*)(wp + (ic * hid + lane) * 4);
        #pragma unroll
        for (int m = 0; m < M; ++m) {
          half4 v = *(const half4*)(A + m * 112 + IOFF[s] + ic * 4);
          a[m] = dot4(v, w, a[m]);
        }
      }
      #pragma unroll
      for (int m = 0; m < M; ++m)
        Hh[m * 160 + HOFF[s] + lane] = (_Float16)fmaxf(a[m], 0.f);
    }
    // upsample: all 64 lanes, lane = e
    {
      const float bu = BU[s][lane];
      float x[M];
      #pragma unroll
      for (int m = 0; m < M; ++m) x[m] = bu;
      const _Float16* wu = WT + OFF_WUT16 + WUT_OFF[s];
      #pragma unroll
      for (int jc = 0; jc < JCNT[s]; ++jc) {
        half4 w = *(const half4*)(wu + (jc * 64 + lane) * 4);
        #pragma unroll
        for (int m = 0; m < M; ++m) {
          half4 h4 = *(const half4*)(Hh + m * 160 + HOFF[s] + jc * 4);
          x[m] = dot4(h4, w, x[m]);
        }
      }
      #pragma unroll
      for (int m = 0; m < M; ++m)
        X[m * 320 + s * 64 + lane] = (_Float16)x[m];
    }
  }

  // ---- fused QKV from h (lane = h*16+d): q = h @ (Wu.Wq) + folded bias ----
  float qr[M][5], kr[M][5], vr[M][5];
  #pragma unroll
  for (int s = 0; s < 5; ++s) {
    const _Float16* wf = WT + OFF_WFT16 + WFT_OFF[s];
    const float* bqp = BQF + s * 192;
    #pragma unroll
    for (int m = 0; m < M; ++m) {
      qr[m][s] = bqp[lane];
      kr[m][s] = bqp[64 + lane];
      vr[m][s] = bqp[128 + lane];
    }
    const int jn = JCNT[s];
    #pragma unroll
    for (int jc = 0; jc < jn; ++jc) {
      half4 wq = *(const half4*)(wf + ((0 * jn + jc) * 64 + lane) * 4);
      half4 wk = *(const half4*)(wf + ((1 * jn + jc) * 64 + lane) * 4);
      half4 wv = *(const half4*)(wf + ((2 * jn + jc) * 64 + lane) * 4);
      #pragma unroll
      for (int m = 0; m < M; ++m) {
        half4 h4 = *(const half4*)(Hh + m * 160 + HOFF[s] + jc * 4);
        qr[m][s] = dot4(h4, wq, qr[m][s]);
        kr[m][s] = dot4(h4, wk, kr[m][s]);
        vr[m][s] = dot4(h4, wv, vr[m][s]);
      }
    }
  }

  // ---- attention in registers (16-lane group reduce over d), f32 ----
  // scores are small/bounded for this net: skip max-subtraction (identical math).
  float orr[M][5];
  #pragma unroll
  for (int m = 0; m < M; ++m) {
    #pragma unroll
    for (int qi = 0; qi < 5; ++qi) {
      float sc[5];
      #pragma unroll
      for (int ki = 0; ki < 5; ++ki) {
        float p = qr[m][qi] * kr[m][ki];
        p += __shfl_xor(p, 1); p += __shfl_xor(p, 2);
        p += __shfl_xor(p, 4); p += __shfl_xor(p, 8);
        sc[ki] = p * 0.25f;
      }
      float ssum = 0.f;
      #pragma unroll
      for (int ki = 0; ki < 5; ++ki) { sc[ki] = __expf(sc[ki]); ssum += sc[ki]; }
      const float inv = 1.0f / ssum;
      float acc = 0.f;
      #pragma unroll
      for (int ki = 0; ki < 5; ++ki) acc += (sc[ki] * inv) * vr[m][ki];
      orr[m][qi] = acc;
    }
  }

  // ---- stage o as f16 ----
  #pragma unroll
  for (int m = 0; m < M; ++m)
    #pragma unroll
    for (int s = 0; s < 5; ++s) O[m * 320 + s * 64 + lane] = (_Float16)orr[m][s];

  // ---- output projection (lane = e) ----
  float att[M][5];
  {
    const float bov = bo[lane];
    #pragma unroll
    for (int m = 0; m < M; ++m)
      #pragma unroll
      for (int s = 0; s < 5; ++s) att[m][s] = bov;
    const _Float16* wo0 = WT + OFF_WOT16;
    #pragma unroll
    for (int hdc = 0; hdc < 16; ++hdc) {
      half4 w = *(const half4*)(wo0 + (hdc * 64 + lane) * 4);
      #pragma unroll
      for (int m = 0; m < M; ++m)
        #pragma unroll
        for (int s = 0; s < 5; ++s) {
          half4 o4 = *(const half4*)(O + m * 320 + s * 64 + hdc * 4);
          att[m][s] = dot4(o4, w, att[m][s]);
        }
    }
  }

  // ---- residual + LayerNorm -> xg bf16 (pre-swizzled, proven) ----
  {
    const float ga = gamma[lane], be = beta[lane];
    #pragma unroll
    for (int m = 0; m < M; ++m) {
      const int r = rowBase + m;
      char* rowp = xg + (size_t)r * 640;
      const int swz = (r & 7) << 4;
      #pragma unroll
      for (int s = 0; s < 5; ++s) {
        const float hv = (float)X[m * 320 + s * 64 + lane] + att[m][s];
        float s1 = hv, s2 = hv * hv;
        #pragma unroll
        for (int off = 32; off >= 1; off >>= 1) {
          s1 += __shfl_xor(s1, off);
          s2 += __shfl_xor(s2, off);
        }
        const float mean = s1 * 0.015625f;
        const float var  = s2 * 0.015625f - mean * mean;
        const float hn = (hv - mean) * rsqrtf(var + 1e-3f) * ga + be;
        *(short*)(rowp + (((s * 64 + lane) * 2) ^ swz)) = f2bs(hn);
      }
    }
  }
}

// ================= kernel B: MLP via MFMA (proven round 3/5) =================
__global__ __launch_bounds__(512) void ace_mlp(
    const char* __restrict__ xg,
    const short* __restrict__ W1F, const short* __restrict__ W2F,
    const float* __restrict__ b1, const float* __restrict__ b2,
    float* __restrict__ out)
{
  __shared__ char smem[81920];
  const int tid  = threadIdx.x;
  const int wave = tid >> 6;     // 0..7
  const int lane = tid & 63;
  const int r15 = lane & 15, g4 = lane >> 4;
  const size_t rowBase = (size_t)blockIdx.x * BROWS;

  {
    const char* src = xg + rowBase * 640;
    #pragma unroll
    for (int i = 0; i < 10; ++i) {
      const int off = i * 8192 + wave * 1024;
      GLOAD_LDS16(src + off + lane * 16, smem + off);
    }
  }
  __syncthreads();

  f32x4 acc1[8][2] = {};
  for (int kk = 0; kk < 10; ++kk) {
    short8 b[2];
    #pragma unroll
    for (int nt = 0; nt < 2; ++nt)
      b[nt] = *(const short8*)(W1F + (((wave * 2 + nt) * 10 + kk) * 64 + lane) * 8);
    #pragma unroll
    for (int mt = 0; mt < 8; ++mt) {
      const int row = mt * 16 + r15;
      short8 a = *(const short8*)(smem + row * 640 + ((kk * 64 + g4 * 16) ^ ((row & 7) << 4)));
      #pragma unroll
      for (int nt = 0; nt < 2; ++nt)
        acc1[mt][nt] = MFMA(a, b[nt], acc1[mt][nt], 0, 0, 0);
    }
  }
  __syncthreads();

  #pragma unroll
  for (int nt = 0; nt < 2; ++nt) {
    const int c = wave * 32 + nt * 16 + r15;
    const float bias = b1[c];
    #pragma unroll
    for (int mt = 0; mt < 8; ++mt)
      #pragma unroll
      for (int j = 0; j < 4; ++j) {
        const int row = mt * 16 + g4 * 4 + j;
        *(short*)(smem + row * 512 + ((c * 2) ^ ((row & 7) << 4))) =
            f2bs(fmaxf(acc1[mt][nt][j] + bias, 0.0f));
      }
  }
  __syncthreads();

  const int nOwn2 = (wave < 2) ? 2 : 1;
  f32x4 acc2[2][8] = {};
  for (int kk = 0; kk < 8; ++kk) {
    short8 b0 = *(const short8*)(W2F + ((wave * 8 + kk) * 64 + lane) * 8);
    short8 b1f = (wave < 2)
        ? *(const short8*)(W2F + (((8 + wave) * 8 + kk) * 64 + lane) * 8) : short8{};
    #pragma unroll
    for (int mt = 0; mt < 8; ++mt) {
      const int row = mt * 16 + r15;
      short8 a = *(const short8*)(smem + row * 512 + ((kk * 64 + g4 * 16) ^ ((row & 7) << 4)));
      acc2[0][mt] = MFMA(a, b0, acc2[0][mt], 0, 0, 0);
      if (wave < 2)
        acc2[1][mt] = MFMA(a, b1f, acc2[1][mt], 0, 0, 0);
    }
  }
  __syncthreads();

  #pragma unroll
  for (int t = 0; t < 2; ++t) {
    if (t < nOwn2) {
      const int c = ((t == 0) ? wave : 8 + wave) * 16 + r15;
      const float bias = b2[c];
      #pragma unroll
      for (int mt = 0; mt < 8; ++mt)
        #pragma unroll
        for (int j = 0; j < 4; ++j) {
          const int row = mt * 16 + g4 * 4 + j;
          *(float*)(smem + (row * 160 + c) * 4) = fmaxf(acc2[t][mt][j] + bias, 0.0f);
        }
    }
  }
  __syncthreads();

  {
    f32x4* dst = (f32x4*)(out + rowBase * 160);
    const f32x4* s4 = (const f32x4*)smem;
    #pragma unroll
    for (int i = 0; i < 10; ++i)
      dst[i * 512 + tid] = s4[i * 512 + tid];
  }
}

extern "C" void kernel_launch(void* const* d_in, const int* in_sizes, int n_in,
                              void* d_out, int out_size, void* d_ws, size_t ws_size,
                              hipStream_t stream) {
  const float* visual  = (const float*)d_in[0];
  const float* audio   = (const float*)d_in[1];
  const float* pose    = (const float*)d_in[2];
  const float* spatial = (const float*)d_in[3];
  const float* timex   = (const float*)d_in[4];
  const float* Wv_p = (const float*)d_in[5];  const float* bv_p = (const float*)d_in[6];
  const float* Wa_p = (const float*)d_in[7];  const float* ba_p = (const float*)d_in[8];
  const float* Wp_p = (const float*)d_in[9];  const float* bp_p = (const float*)d_in[10];
  const float* Ws_p = (const float*)d_in[11]; const float* bs_p = (const float*)d_in[12];
  const float* Wt_p = (const float*)d_in[13]; const float* bt_p = (const float*)d_in[14];
  const float* Wv_u = (const float*)d_in[15]; const float* bv_u = (const float*)d_in[16];
  const float* Wa_u = (const float*)d_in[17]; const float* ba_u = (const float*)d_in[18];
  const float* Wp_u = (const float*)d_in[19]; const float* bp_u = (const float*)d_in[20];
  const float* Ws_u = (const float*)d_in[21]; const float* bs_u = (const float*)d_in[22];
  const float* Wt_u = (const float*)d_in[23]; const float* bt_u = (const float*)d_in[24];
  const float* Wq  = (const float*)d_in[25];  const float* bq  = (const float*)d_in[26];
  const float* Wk  = (const float*)d_in[27];  const float* bk  = (const float*)d_in[28];
  const float* Wvv = (const float*)d_in[29];  const float* bvv = (const float*)d_in[30];
  const float* Wo  = (const float*)d_in[31];  const float* bo  = (const float*)d_in[32];
  const float* gamma = (const float*)d_in[33]; const float* beta = (const float*)d_in[34];
  const float* W1 = (const float*)d_in[35];   const float* b1 = (const float*)d_in[36];
  const float* W2 = (const float*)d_in[37];   const float* b2 = (const float*)d_in[38];
  float* out = (float*)d_out;

  short*     WS  = (short*)d_ws;                       // bf16 MLP tables [0, 245760) B
  _Float16*  WT  = (_Float16*)((char*)d_ws + 245760);  // f16 front tables, 97664 B
  float*     BQF = (float*)((char*)d_ws + 344064);     // f32 fused QKV bias, 3840 B
  char*      xg  = (char*)d_ws + 524288;               // bf16 [NROWS][320] pre-swizzled, 80 MiB

  hipLaunchKernelGGL(pack_weights, dim3(480), dim3(256), 0, stream, W1, W2, WS);
  hipLaunchKernelGGL(pack16, dim3((PACK_N + 255) / 256), dim3(256), 0, stream,
                     Wv_p, Wa_p, Wp_p, Ws_p, Wt_p,
                     Wv_u, Wa_u, Wp_u, Ws_u, Wt_u,
                     bv_u, ba_u, bp_u, bs_u, bt_u,
                     Wq, Wk, Wvv, bq, bk, bvv, Wo, WT, BQF);

  hipLaunchKernelGGL(ace_front4, dim3(NROWS / (WAVES * M)), dim3(256), 0, stream,
                     visual, audio, pose, spatial, timex,
                     bv_p, ba_p, bp_p, bs_p, bt_p,
                     bv_u, ba_u, bp_u, bs_u, bt_u,
                     bo, gamma, beta, WT, BQF, xg);

  hipLaunchKernelGGL(ace_mlp, dim3(NROWS / BROWS), dim3(512), 0, stream,
                     xg, WS, WS + 81920, b1, b2, out);
}

// Round 17
// 383.591 us; speedup vs baseline: 1.3879x; 1.3879x over previous
//
#include <hip/hip_runtime.h>
#include <hip/hip_bf16.h>
#include <math.h>

// Round 17: r16 with the staging-overlap fix -- IN region row stride 112 -> 128
// (r16 bug: timex at IOFF8=104 ends at 114 > 112, colliding with next row's visual).
//  pack_weights: W1,W2 -> bf16 MFMA B-frag tables (proven)
//  pack16:       front weights -> f16 chunk-of-8 tables + f32 fused QKV bias
//  ace_front5:   branches + fused-QKV + attn + Wo + LN (dot8 + DPP reduce) -> xg bf16
//  ace_mlp:      proven MFMA MLP
// B=131072, E=64, H=4, D=16, S=5. Out: (B,160) fp32.

#define NROWS 131072
#define M 2
#define WAVES 4
#define BROWS 128

typedef __attribute__((ext_vector_type(8))) short short8;
typedef __attribute__((ext_vector_type(4))) float f32x4;
typedef __attribute__((ext_vector_type(8))) _Float16 half8;

__device__ __forceinline__ short f2bs(float f) {
  __hip_bfloat16 h = __float2bfloat16(f);
  return *reinterpret_cast<short*>(&h);
}

__device__ __forceinline__ float dot8(half8 a, half8 b, float c) {
#if __has_builtin(__builtin_amdgcn_fdot2)
  c = __builtin_amdgcn_fdot2(__builtin_shufflevector(a, a, 0, 1),
                             __builtin_shufflevector(b, b, 0, 1), c, false);
  c = __builtin_amdgcn_fdot2(__builtin_shufflevector(a, a, 2, 3),
                             __builtin_shufflevector(b, b, 2, 3), c, false);
  c = __builtin_amdgcn_fdot2(__builtin_shufflevector(a, a, 4, 5),
                             __builtin_shufflevector(b, b, 4, 5), c, false);
  c = __builtin_amdgcn_fdot2(__builtin_shufflevector(a, a, 6, 7),
                             __builtin_shufflevector(b, b, 6, 7), c, false);
#else
  #pragma unroll
  for (int i = 0; i < 8; ++i) c += (float)a[i] * (float)b[i];
#endif
  return c;
}

// DPP add: v += v[perm(lane)], pure VALU (no LDS pipe).
template <int CTRL>
__device__ __forceinline__ float dppadd(float v) {
  int x = __builtin_amdgcn_update_dpp(0, __builtin_bit_cast(int, v), CTRL, 0xf, 0xf, true);
  return v + __builtin_bit_cast(float, x);
}
// full 16-lane sum: xor1, xor2, half_mirror(==xor4 after quads), mirror(==xor8 after halves)
__device__ __forceinline__ float sum16(float v) {
  v = dppadd<0xB1>(v);   // quad_perm [1,0,3,2]
  v = dppadd<0x4E>(v);   // quad_perm [2,3,0,1]
  v = dppadd<0x141>(v);  // row_half_mirror
  v = dppadd<0x140>(v);  // row_mirror
  return v;
}

#define MFMA __builtin_amdgcn_mfma_f32_16x16x32_bf16
#define GLOAD_LDS16(g, l) __builtin_amdgcn_global_load_lds( \
    (const __attribute__((address_space(1))) void*)(g),     \
    (__attribute__((address_space(3))) void*)(l), 16, 0, 0)

// f16 table layout (element offsets), chunk-of-8:
#define OFF_WUT8  4224
#define OFF_WFT8  14464
#define OFF_WOT8  45184
#define WT16_N    49280
#define PACK_N    (WT16_N + 960)   // + f32 BQF[5][3][64]

// ---------------- pack 1: W1,W2 -> bf16 fragment-ordered (proven) ----------------
__global__ void pack_weights(const float* __restrict__ W1, const float* __restrict__ W2,
                             short* __restrict__ ws) {
  int idx = blockIdx.x * blockDim.x + threadIdx.x;
  if (idx < 81920) {
    int i = idx & 7, lane = (idx >> 3) & 63;
    int t = idx >> 9;                 // ntg*10 + kk
    int kk = t % 10, ntg = t / 10;
    int n = ntg * 16 + (lane & 15);
    int k = kk * 32 + (lane >> 4) * 8 + i;
    ws[idx] = f2bs(W1[k * 256 + n]);
  } else if (idx < 81920 + 40960) {
    int j = idx - 81920;
    int i = j & 7, lane = (j >> 3) & 63;
    int t = j >> 9;                   // ntg*8 + kk
    int kk = t & 7, ntg = t >> 3;
    int n = ntg * 16 + (lane & 15);
    int k = kk * 32 + (lane >> 4) * 8 + i;
    ws[81920 + j] = f2bs(W2[k * 160 + n]);
  }
}

// ---------------- pack 16: f16 chunk-of-8 front tables + f32 fused QKV bias ----------------
__global__ void pack16(
    const float* __restrict__ Wv_p, const float* __restrict__ Wa_p,
    const float* __restrict__ Wp_p, const float* __restrict__ Ws_p,
    const float* __restrict__ Wt_p,
    const float* __restrict__ Wv_u, const float* __restrict__ Wa_u,
    const float* __restrict__ Wp_u, const float* __restrict__ Ws_u,
    const float* __restrict__ Wt_u,
    const float* __restrict__ bv_u, const float* __restrict__ ba_u,
    const float* __restrict__ bp_u, const float* __restrict__ bs_u,
    const float* __restrict__ bt_u,
    const float* __restrict__ Wq, const float* __restrict__ Wk,
    const float* __restrict__ Wvv,
    const float* __restrict__ bq, const float* __restrict__ bk,
    const float* __restrict__ bvv,
    const float* __restrict__ Wo,
    _Float16* __restrict__ wt, float* __restrict__ bqf)
{
  int idx = blockIdx.x * blockDim.x + threadIdx.x;
  if (idx >= PACK_N) return;
  const float* WP[5] = {Wv_p, Wa_p, Wp_p, Ws_p, Wt_p};
  const float* WU[5] = {Wv_u, Wa_u, Wp_u, Ws_u, Wt_u};
  const float* BU[5] = {bv_u, ba_u, bp_u, bs_u, bt_u};
  const float* WT3[3] = {Wq, Wk, Wvv};
  const float* BT3[3] = {bq, bk, bvv};
  const int INs[5]  = {14, 17, 51, 7, 10};
  const int HIDs[5] = {32, 64, 32, 16, 16};
  const int ICNT8[5] = {2, 3, 7, 1, 2};
  const int JC8[5]   = {4, 8, 4, 2, 2};

  if (idx < OFF_WUT8) {                                // WPT8
    int r = idx, s = 0;
    while (r >= ICNT8[s] * HIDs[s] * 8) { r -= ICNT8[s] * HIDs[s] * 8; ++s; }
    int ic8 = r / (HIDs[s] * 8);
    int j   = (r / 8) % HIDs[s];
    int c   = r & 7;
    int i   = ic8 * 8 + c;
    wt[idx] = (_Float16)((i < INs[s]) ? WP[s][i * HIDs[s] + j] : 0.f);
  } else if (idx < OFF_WFT8) {                         // WUT8
    int r = idx - OFF_WUT8, s = 0;
    while (r >= JC8[s] * 512) { r -= JC8[s] * 512; ++s; }
    int jc8 = r / 512;
    int e   = (r / 8) & 63;
    int c   = r & 7;
    wt[idx] = (_Float16)(WU[s][(jc8 * 8 + c) * 64 + e]);
  } else if (idx < OFF_WOT8) {                         // WFT8
    int r = idx - OFF_WFT8, s = 0;
    while (r >= 3 * JC8[s] * 512) { r -= 3 * JC8[s] * 512; ++s; }
    int t  = r / (JC8[s] * 512);
    int r2 = r % (JC8[s] * 512);
    int jc8 = r2 / 512;
    int hd  = (r2 / 8) & 63;
    int c   = r2 & 7;
    int j   = jc8 * 8 + c;
    float acc = 0.f;
    for (int e = 0; e < 64; ++e) acc += WU[s][j * 64 + e] * WT3[t][e * 64 + hd];
    wt[idx] = (_Float16)acc;
  } else if (idx < WT16_N) {                           // WOT8
    int r = idx - OFF_WOT8;
    int hdc8 = r / 512;
    int e    = (r / 8) & 63;
    int c    = r & 7;
    wt[idx] = (_Float16)(Wo[(hdc8 * 8 + c) * 64 + e]);
  } else {                                             // BQF
    int c = idx - WT16_N;               // [0,960)
    int s = c / 192, rem = c % 192, t = rem >> 6, hd = rem & 63;
    float acc = BT3[t][hd];
    for (int e = 0; e < 64; ++e) acc += BU[s][e] * WT3[t][e * 64 + hd];
    bqf[c] = acc;
  }
}

// ================= kernel A: front, f16 dot8 + DPP reduce, 4 waves/EU =================
__global__ __launch_bounds__(256, 4) void ace_front5(
    const float* __restrict__ visual, const float* __restrict__ audio,
    const float* __restrict__ pose,   const float* __restrict__ spatial,
    const float* __restrict__ timex,
    const float* __restrict__ bv_p, const float* __restrict__ ba_p,
    const float* __restrict__ bp_p, const float* __restrict__ bs_p,
    const float* __restrict__ bt_p,
    const float* __restrict__ bv_u, const float* __restrict__ ba_u,
    const float* __restrict__ bp_u, const float* __restrict__ bs_u,
    const float* __restrict__ bt_u,
    const float* __restrict__ bo,
    const float* __restrict__ gamma, const float* __restrict__ beta,
    const _Float16* __restrict__ WT, const float* __restrict__ BQF,
    char* __restrict__ xg)   // bf16 [NROWS][320], byte (col*2)^((row&7)<<4)
{
  // per-wave f16 LDS: in @0 [m][128] (stride 128: ends<=114, reads<=119 in zero pad),
  //                   h @256 [m][160], x @576 [m][5][64], o @1216 [m][5][64]
  __shared__ __align__(16) _Float16 lds[WAVES][1920];
  const int tid  = threadIdx.x;
  const int wave = tid >> 6;
  const int lane = tid & 63;
  _Float16* A  = lds[wave];
  _Float16* Hh = A + 256;
  _Float16* X  = A + 576;
  _Float16* O  = A + 1216;
  const int rowBase = (blockIdx.x * WAVES + wave) * M;

  const int HIDs[5] = {32, 64, 32, 16, 16};
  const int ICNT8[5] = {2, 3, 7, 1, 2};
  const int JC8[5]   = {4, 8, 4, 2, 2};
  const int IOFF8[5] = {0, 16, 40, 96, 104};
  const int HOFF[5]  = {0, 32, 96, 128, 144};
  const int WPT8_OFF[5] = {0, 512, 2048, 3840, 3968};
  const int WUT8_OFF[5] = {0, 2048, 6144, 8192, 9216};
  const int WFT8_OFF[5] = {0, 6144, 18432, 24576, 27648};
  const float* BP[5] = {bv_p, ba_p, bp_p, bs_p, bt_p};
  const float* BU[5] = {bv_u, ba_u, bp_u, bs_u, bt_u};

  // ---- zero full IN region [0..256), then stage raw inputs as f16 ----
  #pragma unroll
  for (int k2 = 0; k2 < 4; ++k2) A[k2 * 64 + lane] = (_Float16)0.f;
  #pragma unroll
  for (int m = 0; m < M; ++m) {
    const int r = rowBase + m;
    if (lane < 14) A[m * 128 +   0 + lane] = (_Float16)visual [r * 14 + lane];
    if (lane < 17) A[m * 128 +  16 + lane] = (_Float16)audio  [r * 17 + lane];
    if (lane < 51) A[m * 128 +  40 + lane] = (_Float16)pose   [r * 51 + lane];
    if (lane <  7) A[m * 128 +  96 + lane] = (_Float16)spatial[r *  7 + lane];
    if (lane < 10) A[m * 128 + 104 + lane] = (_Float16)timex  [r * 10 + lane];
  }

  // ---- proj (relu) + upsample per modality ----
  #pragma unroll
  for (int s = 0; s < 5; ++s) {
    const int hid = HIDs[s];
    if (lane < hid) {
      const float bp = BP[s][lane];
      float a0 = bp, a1 = bp;
      const _Float16* wp = WT + WPT8_OFF[s];
      #pragma unroll
      for (int ic = 0; ic < ICNT8[s]; ++ic) {
        half8 w  = *(const half8*)(wp + (ic * hid + lane) * 8);
        half8 v0 = *(const half8*)(A + 0 * 128 + IOFF8[s] + ic * 8);
        half8 v1 = *(const half8*)(A + 1 * 128 + IOFF8[s] + ic * 8);
        a0 = dot8(v0, w, a0);
        a1 = dot8(v1, w, a1);
      }
      Hh[0 * 160 + HOFF[s] + lane] = (_Float16)fmaxf(a0, 0.f);
      Hh[1 * 160 + HOFF[s] + lane] = (_Float16)fmaxf(a1, 0.f);
    }
    // upsample: all 64 lanes, lane = e
    {
      const float bu = BU[s][lane];
      float x0 = bu, x1 = bu;
      const _Float16* wu = WT + OFF_WUT8 + WUT8_OFF[s];
      #pragma unroll
      for (int jc = 0; jc < JC8[s]; ++jc) {
        half8 w  = *(const half8*)(wu + (jc * 64 + lane) * 8);
        half8 h0 = *(const half8*)(Hh + 0 * 160 + HOFF[s] + jc * 8);
        half8 h1 = *(const half8*)(Hh + 1 * 160 + HOFF[s] + jc * 8);
        x0 = dot8(h0, w, x0);
        x1 = dot8(h1, w, x1);
      }
      X[0 * 320 + s * 64 + lane] = (_Float16)x0;
      X[1 * 320 + s * 64 + lane] = (_Float16)x1;
    }
  }

  // ---- fused QKV from h (lane = h*16+d): q = h @ (Wu.Wq) + folded bias ----
  float qr[M][5], kr[M][5], vr[M][5];
  #pragma unroll
  for (int s = 0; s < 5; ++s) {
    const _Float16* wf = WT + OFF_WFT8 + WFT8_OFF[s];
    const float* bqp = BQF + s * 192;
    #pragma unroll
    for (int m = 0; m < M; ++m) {
      qr[m][s] = bqp[lane];
      kr[m][s] = bqp[64 + lane];
      vr[m][s] = bqp[128 + lane];
    }
    const int jn = JC8[s];
    #pragma unroll
    for (int jc = 0; jc < jn; ++jc) {
      half8 wq = *(const half8*)(wf + ((0 * jn + jc) * 64 + lane) * 8);
      half8 wk = *(const half8*)(wf + ((1 * jn + jc) * 64 + lane) * 8);
      half8 wv = *(const half8*)(wf + ((2 * jn + jc) * 64 + lane) * 8);
      #pragma unroll
      for (int m = 0; m < M; ++m) {
        half8 h8 = *(const half8*)(Hh + m * 160 + HOFF[s] + jc * 8);
        qr[m][s] = dot8(h8, wq, qr[m][s]);
        kr[m][s] = dot8(h8, wk, kr[m][s]);
        vr[m][s] = dot8(h8, wv, vr[m][s]);
      }
    }
  }

  // ---- attention in registers: 16-lane DPP reduce, no-max softmax ----
  float orr[M][5];
  #pragma unroll
  for (int m = 0; m < M; ++m) {
    #pragma unroll
    for (int qi = 0; qi < 5; ++qi) {
      float sc[5];
      #pragma unroll
      for (int ki = 0; ki < 5; ++ki)
        sc[ki] = sum16(qr[m][qi] * kr[m][ki]) * 0.25f;
      float ssum = 0.f;
      #pragma unroll
      for (int ki = 0; ki < 5; ++ki) { sc[ki] = __expf(sc[ki]); ssum += sc[ki]; }
      const float inv = 1.0f / ssum;
      float acc = 0.f;
      #pragma unroll
      for (int ki = 0; ki < 5; ++ki) acc += (sc[ki] * inv) * vr[m][ki];
      orr[m][qi] = acc;
    }
  }

  // ---- stage o as f16 ----
  #pragma unroll
  for (int m = 0; m < M; ++m)
    #pragma unroll
    for (int s = 0; s < 5; ++s) O[m * 320 + s * 64 + lane] = (_Float16)orr[m][s];

  // ---- output projection (lane = e) ----
  float att[M][5];
  {
    const float bov = bo[lane];
    #pragma unroll
    for (int m = 0; m < M; ++m)
      #pragma unroll
      for (int s = 0; s < 5; ++s) att[m][s] = bov;
    const _Float16* wo0 = WT + OFF_WOT8;
    #pragma unroll
    for (int hdc = 0; hdc < 8; ++hdc) {
      half8 w = *(const half8*)(wo0 + (hdc * 64 + lane) * 8);
      #pragma unroll
      for (int m = 0; m < M; ++m)
        #pragma unroll
        for (int s = 0; s < 5; ++s) {
          half8 o8 = *(const half8*)(O + m * 320 + s * 64 + hdc * 8);
          att[m][s] = dot8(o8, w, att[m][s]);
        }
    }
  }

  // ---- residual + LayerNorm -> xg bf16 (pre-swizzled, proven) ----
  {
    const float ga = gamma[lane], be = beta[lane];
    #pragma unroll
    for (int m = 0; m < M; ++m) {
      const int r = rowBase + m;
      char* rowp = xg + (size_t)r * 640;
      const int swz = (r & 7) << 4;
      #pragma unroll
      for (int s = 0; s < 5; ++s) {
        const float hv = (float)X[m * 320 + s * 64 + lane] + att[m][s];
        float s1 = sum16(hv);
        float s2 = sum16(hv * hv);
        s1 += __shfl_xor(s1, 16); s2 += __shfl_xor(s2, 16);
        s1 += __shfl_xor(s1, 32); s2 += __shfl_xor(s2, 32);
        const float mean = s1 * 0.015625f;
        const float var  = s2 * 0.015625f - mean * mean;
        const float hn = (hv - mean) * rsqrtf(var + 1e-3f) * ga + be;
        *(short*)(rowp + (((s * 64 + lane) * 2) ^ swz)) = f2bs(hn);
      }
    }
  }
}

// ================= kernel B: MLP via MFMA (proven round 3/5) =================
__global__ __launch_bounds__(512) void ace_mlp(
    const char* __restrict__ xg,
    const short* __restrict__ W1F, const short* __restrict__ W2F,
    const float* __restrict__ b1, const float* __restrict__ b2,
    float* __restrict__ out)
{
  __shared__ char smem[81920];
  const int tid  = threadIdx.x;
  const int wave = tid >> 6;     // 0..7
  const int lane = tid & 63;
  const int r15 = lane & 15, g4 = lane >> 4;
  const size_t rowBase = (size_t)blockIdx.x * BROWS;

  {
    const char* src = xg + rowBase * 640;
    #pragma unroll
    for (int i = 0; i < 10; ++i) {
      const int off = i * 8192 + wave * 1024;
      GLOAD_LDS16(src + off + lane * 16, smem + off);
    }
  }
  __syncthreads();

  f32x4 acc1[8][2] = {};
  for (int kk = 0; kk < 10; ++kk) {
    short8 b[2];
    #pragma unroll
    for (int nt = 0; nt < 2; ++nt)
      b[nt] = *(const short8*)(W1F + (((wave * 2 + nt) * 10 + kk) * 64 + lane) * 8);
    #pragma unroll
    for (int mt = 0; mt < 8; ++mt) {
      const int row = mt * 16 + r15;
      short8 a = *(const short8*)(smem + row * 640 + ((kk * 64 + g4 * 16) ^ ((row & 7) << 4)));
      #pragma unroll
      for (int nt = 0; nt < 2; ++nt)
        acc1[mt][nt] = MFMA(a, b[nt], acc1[mt][nt], 0, 0, 0);
    }
  }
  __syncthreads();

  #pragma unroll
  for (int nt = 0; nt < 2; ++nt) {
    const int c = wave * 32 + nt * 16 + r15;
    const float bias = b1[c];
    #pragma unroll
    for (int mt = 0; mt < 8; ++mt)
      #pragma unroll
      for (int j = 0; j < 4; ++j) {
        const int row = mt * 16 + g4 * 4 + j;
        *(short*)(smem + row * 512 + ((c * 2) ^ ((row & 7) << 4))) =
            f2bs(fmaxf(acc1[mt][nt][j] + bias, 0.0f));
      }
  }
  __syncthreads();

  const int nOwn2 = (wave < 2) ? 2 : 1;
  f32x4 acc2[2][8] = {};
  for (int kk = 0; kk < 8; ++kk) {
    short8 b0 = *(const short8*)(W2F + ((wave * 8 + kk) * 64 + lane) * 8);
    short8 b1f = (wave < 2)
        ? *(const short8*)(W2F + (((8 + wave) * 8 + kk) * 64 + lane) * 8) : short8{};
    #pragma unroll
    for (int mt = 0; mt < 8; ++mt) {
      const int row = mt * 16 + r15;
      short8 a = *(const short8*)(smem + row * 512 + ((kk * 64 + g4 * 16) ^ ((row & 7) << 4)));
      acc2[0][mt] = MFMA(a, b0, acc2[0][mt], 0, 0, 0);
      if (wave < 2)
        acc2[1][mt] = MFMA(a, b1f, acc2[1][mt], 0, 0, 0);
    }
  }
  __syncthreads();

  #pragma unroll
  for (int t = 0; t < 2; ++t) {
    if (t < nOwn2) {
      const int c = ((t == 0) ? wave : 8 + wave) * 16 + r15;
      const float bias = b2[c];
      #pragma unroll
      for (int mt = 0; mt < 8; ++mt)
        #pragma unroll
        for (int j = 0; j < 4; ++j) {
          const int row = mt * 16 + g4 * 4 + j;
          *(float*)(smem + (row * 160 + c) * 4) = fmaxf(acc2[t][mt][j] + bias, 0.0f);
        }
    }
  }
  __syncthreads();

  {
    f32x4* dst = (f32x4*)(out + rowBase * 160);
    const f32x4* s4 = (const f32x4*)smem;
    #pragma unroll
    for (int i = 0; i < 10; ++i)
      dst[i * 512 + tid] = s4[i * 512 + tid];
  }
}

extern "C" void kernel_launch(void* const* d_in, const int* in_sizes, int n_in,
                              void* d_out, int out_size, void* d_ws, size_t ws_size,
                              hipStream_t stream) {
  const float* visual  = (const float*)d_in[0];
  const float* audio   = (const float*)d_in[1];
  const float* pose    = (const float*)d_in[2];
  const float* spatial = (const float*)d_in[3];
  const float* timex   = (const float*)d_in[4];
  const float* Wv_p = (const float*)d_in[5];  const float* bv_p = (const float*)d_in[6];
  const float* Wa_p = (const float*)d_in[7];  const float* ba_p = (const float*)d_in[8];
  const float* Wp_p = (const float*)d_in[9];  const float* bp_p = (const float*)d_in[10];
  const float* Ws_p = (const float*)d_in[11]; const float* bs_p = (const float*)d_in[12];
  const float* Wt_p = (const float*)d_in[13]; const float* bt_p = (const float*)d_in[14];
  const float* Wv_u = (const float*)d_in[15]; const float* bv_u = (const float*)d_in[16];
  const float* Wa_u = (const float*)d_in[17]; const float* ba_u = (const float*)d_in[18];
  const float* Wp_u = (const float*)d_in[19]; const float* bp_u = (const float*)d_in[20];
  const float* Ws_u = (const float*)d_in[21]; const float* bs_u = (const float*)d_in[22];
  const float* Wt_u = (const float*)d_in[23]; const float* bt_u = (const float*)d_in[24];
  const float* Wq  = (const float*)d_in[25];  const float* bq  = (const float*)d_in[26];
  const float* Wk  = (const float*)d_in[27];  const float* bk  = (const float*)d_in[28];
  const float* Wvv = (const float*)d_in[29];  const float* bvv = (const float*)d_in[30];
  const float* Wo  = (const float*)d_in[31];  const float* bo  = (const float*)d_in[32];
  const float* gamma = (const float*)d_in[33]; const float* beta = (const float*)d_in[34];
  const float* W1 = (const float*)d_in[35];   const float* b1 = (const float*)d_in[36];
  const float* W2 = (const float*)d_in[37];   const float* b2 = (const float*)d_in[38];
  float* out = (float*)d_out;

  short*     WS  = (short*)d_ws;                       // bf16 MLP tables [0, 245760) B
  _Float16*  WT  = (_Float16*)((char*)d_ws + 245760);  // f16 front tables, 98560 B
  float*     BQF = (float*)((char*)d_ws + 345088);     // f32 fused QKV bias, 3840 B
  char*      xg  = (char*)d_ws + 524288;               // bf16 [NROWS][320] pre-swizzled, 80 MiB

  hipLaunchKernelGGL(pack_weights, dim3(480), dim3(256), 0, stream, W1, W2, WS);
  hipLaunchKernelGGL(pack16, dim3((PACK_N + 255) / 256), dim3(256), 0, stream,
                     Wv_p, Wa_p, Wp_p, Ws_p, Wt_p,
                     Wv_u, Wa_u, Wp_u, Ws_u, Wt_u,
                     bv_u, ba_u, bp_u, bs_u, bt_u,
                     Wq, Wk, Wvv, bq, bk, bvv, Wo, WT, BQF);

  hipLaunchKernelGGL(ace_front5, dim3(NROWS / (WAVES * M)), dim3(256), 0, stream,
                     visual, audio, pose, spatial, timex,
                     bv_p, ba_p, bp_p, bs_p, bt_p,
                     bv_u, ba_u, bp_u, bs_u, bt_u,
                     bo, gamma, beta, WT, BQF, xg);

  hipLaunchKernelGGL(ace_mlp, dim3(NROWS / BROWS), dim3(512), 0, stream,
                     xg, WS, WS + 81920, b1, b2, out);
}